// Round 3
// baseline (314.892 us; speedup 1.0000x reference)
//
#include <hip/hip_runtime.h>
#include <math.h>

#define BATCH 8
#define NPTS  4096
#define CF    256
#define TOPK  16
#define TOTQ  (BATCH*NPTS)
#define EPOFF ((size_t)TOTQ*CF)

typedef __attribute__((ext_vector_type(8))) short bf16x8;
typedef __attribute__((ext_vector_type(4))) float f32x4;

__device__ __forceinline__ unsigned short f2bf(float x) {
    union { float f; unsigned u; } a; a.f = x;
    unsigned r = a.u + 0x7fffu + ((a.u >> 16) & 1u);   // RNE
    return (unsigned short)(r >> 16);
}
__device__ __forceinline__ float bf2f(unsigned short h) {
    union { float f; unsigned u; } a; a.u = ((unsigned)h) << 16; return a.f;
}
__device__ __forceinline__ void gl_lds16(const void* g, void* l) {
    __builtin_amdgcn_global_load_lds(
        (const __attribute__((address_space(1))) unsigned int*)g,
        (__attribute__((address_space(3))) unsigned int*)l, 16, 0, 0);
}

// ---------------------------------------------------------------------------
// combined prep: xyz -> float4 table; r_w/e_w1 -> bf16 hi/lo MFMA-frag tables
// ---------------------------------------------------------------------------
__global__ __launch_bounds__(256) void prep_k(
    const float* __restrict__ xyz, float4* __restrict__ tab,
    const float* __restrict__ rw, const float* __restrict__ ew1,
    unsigned short* __restrict__ rwh, unsigned short* __restrict__ rwl,
    unsigned short* __restrict__ ewh, unsigned short* __restrict__ ewl)
{
    int t = blockIdx.x*256 + threadIdx.x;
    if (t < TOTQ) {
        float x = xyz[3*t], y = xyz[3*t+1], z = xyz[3*t+2];
        tab[t] = make_float4(x, y, z, x*x + y*y + z*z);
    }
    if (t < 65536) {                       // r_w [256][256]
        int k = t >> 8, n = t & 255;
        float x = rw[t];
        unsigned short h = f2bf(x);
        unsigned short l = f2bf(x - bf2f(h));
        int dst = (((k>>5)*16 + (n>>4)) << 9) + ((k>>3)&3)*128 + (n&15)*8 + (k&7);
        rwh[dst] = h; rwl[dst] = l;
    }
    if (t < 288*64) {                      // e_w1 [288][64] (zero-padded K)
        int k = t >> 6, n = t & 63;
        float x = (k < 272) ? ew1[k*64 + n] : 0.f;
        unsigned short h = f2bf(x);
        unsigned short l = f2bf(x - bf2f(h));
        int dst = (((k>>5)*4 + (n>>4)) << 9) + ((k>>3)&3)*128 + (n&15)*8 + (k&7);
        ewh[dst] = h; ewl[dst] = l;
    }
}

// ---------------------------------------------------------------------------
// kernel A: brute-force KNN, 8 threads/query (quarter = wave, 512 cand each),
// min/max insert chain, 2-stage publish + hierarchical merge, geo + MLP.
// 512 blocks x 512 threads; 64 queries/block.
// ---------------------------------------------------------------------------
__global__ __launch_bounds__(512, 4) void knn_geo_k(
    const float4* __restrict__ tab,
    const float* __restrict__ g_w1, const float* __restrict__ g_b1,
    const float* __restrict__ g_lnw, const float* __restrict__ g_lnb,
    const float* __restrict__ g_w2, const float* __restrict__ g_b2,
    float* __restrict__ geo_out)
{
    __shared__ float2 lstS[8][512];          // 32 KB scan buffers / publish area
    __shared__ float2 M1[16][64];            // 8 KB merged quarters 0-3
    __shared__ float4 coords[64][TOPK+1];    // 17.4 KB
    __shared__ float s_w1[320], s_b1[32], s_lnw[32], s_lnb[32], s_w2[512], s_b2[16];

    const int tid = threadIdx.x;
    if (tid < 320) s_w1[tid] = g_w1[tid];
    s_w2[tid & 511] = g_w2[tid & 511];
    if (tid < 32) { s_b1[tid] = g_b1[tid]; s_lnw[tid] = g_lnw[tid]; s_lnb[tid] = g_lnb[tid]; }
    if (tid < 16) s_b2[tid] = g_b2[tid];

    const int ql = tid & 63;                 // query within block
    const int qg = blockIdx.x*64 + ql;
    const int wv = tid >> 6;                 // wave = quarter 0..7
    const int b  = blockIdx.x >> 6;          // 64 blocks per batch
    const float4* __restrict__ ctab = tab + b*NPTS;
    const int ibase = __builtin_amdgcn_readfirstlane(wv << 9);   // 512-cand slice

    float4 q4 = tab[qg];
    const float qx = q4.x, qy = q4.y, qz = q4.z, qs = q4.w;

    float vals[TOPK]; int idxs[TOPK];
    #pragma unroll
    for (int j = 0; j < TOPK; ++j) { vals[j] = -INFINITY; idxs[j] = 0; }
    int   cnt = 0;
    float thr = -INFINITY;

    auto flushbuf = [&]() {
        for (int e = 0; e < cnt; ++e) {
            float2 en = lstS[e][tid];
            float pv = en.x;
            int   pj = __float_as_int(en.y);
            if (pv > vals[TOPK-1]) {
                // min/max shift-insert: v[j] = max(v[j], min(pv, v[j-1]))
                #pragma unroll
                for (int j = TOPK-1; j >= 1; --j) {
                    bool ca = pv > vals[j];
                    bool cb = pv > vals[j-1];      // CSE with next level's ca
                    float t = fminf(pv, vals[j-1]);
                    vals[j] = fmaxf(vals[j], t);
                    int ish = cb ? idxs[j-1] : pj;
                    idxs[j] = ca ? ish : idxs[j];
                }
                bool c0 = pv > vals[0];
                idxs[0] = c0 ? pj : idxs[0];
                vals[0] = fmaxf(vals[0], pv);
            }
        }
    };

    #define EVALC(c, gi)                                                     \
        {                                                                    \
            float dot = fmaf(qx, (c).x, fmaf(qy, (c).y, qz*(c).z));          \
            float pd  = fmaf(2.f, dot, -(qs + (c).w));                       \
            if (pd > thr) {                                                  \
                lstS[cnt][tid] = make_float2(pd, __int_as_float(gi));        \
                ++cnt;                                                       \
            }                                                                \
        }

    {
        const float4* cptr = ctab + ibase;
        float4 A0 = cptr[0], A1 = cptr[1], A2 = cptr[2], A3 = cptr[3];
        for (int ib = 0; ib < 512; ib += 8) {
            float4 B0 = cptr[ib+4], B1 = cptr[ib+5], B2 = cptr[ib+6], B3 = cptr[ib+7];
            EVALC(A0, ibase+ib+0); EVALC(A1, ibase+ib+1);
            EVALC(A2, ibase+ib+2); EVALC(A3, ibase+ib+3);
            if (__any(cnt > 4)) { flushbuf(); cnt = 0; thr = vals[TOPK-1]; }
            A0 = cptr[ib+8]; A1 = cptr[ib+9]; A2 = cptr[ib+10]; A3 = cptr[ib+11]; // 64B overread at end: lands in ws, unused
            EVALC(B0, ibase+ib+4); EVALC(B1, ibase+ib+5);
            EVALC(B2, ibase+ib+6); EVALC(B3, ibase+ib+7);
            if (__any(cnt > 4)) { flushbuf(); cnt = 0; thr = vals[TOPK-1]; }
        }
        flushbuf();
    }
    #undef EVALC

    float2 (*lstP)[256] = (float2(*)[256])&lstS[0][0];   // publish view [16][256]

    __syncthreads();
    // stage A: waves 0-3 publish sorted lists
    if (wv < 4) {
        #pragma unroll
        for (int e = 0; e < TOPK; ++e)
            lstP[e][wv*64 + ql] = make_float2(vals[e], __int_as_float(idxs[e]));
    }
    __syncthreads();
    // wave 0: 4-way merge quarters 0-3 -> M1
    if (tid < 64) {
        const int q = tid;
        int p0 = 0, p1 = 0, p2 = 0, p3 = 0;
        for (int r = 0; r < TOPK; ++r) {
            float2 h0 = lstP[p0][q];
            float2 h1 = lstP[p1][64 + q];
            float2 h2 = lstP[p2][128 + q];
            float2 h3 = lstP[p3][192 + q];
            float best = h0.x; int bj = __float_as_int(h0.y); int bs = 0;
            if (h1.x > best) { best = h1.x; bj = __float_as_int(h1.y); bs = 1; }
            if (h2.x > best) { best = h2.x; bj = __float_as_int(h2.y); bs = 2; }
            if (h3.x > best) { best = h3.x; bj = __float_as_int(h3.y); bs = 3; }
            p0 += (bs == 0); p1 += (bs == 1); p2 += (bs == 2); p3 += (bs == 3);
            M1[r][q] = make_float2(best, __int_as_float(bj));
        }
    }
    __syncthreads();
    // stage B: waves 4-7 publish
    if (wv >= 4) {
        #pragma unroll
        for (int e = 0; e < TOPK; ++e)
            lstP[e][(wv-4)*64 + ql] = make_float2(vals[e], __int_as_float(idxs[e]));
    }
    __syncthreads();

    // wave 0: 5-way merge (M1 + quarters 4-7) + geometry + geo MLP
    if (tid < 64) {
        const int q = tid;
        int pm = 0, p4 = 0, p5 = 0, p6 = 0, p7 = 0;
        float sx = 0, sy = 0, sz = 0;
        for (int r = 0; r < TOPK; ++r) {
            float2 hm = M1[pm][q];
            float2 h4 = lstP[p4][q];
            float2 h5 = lstP[p5][64 + q];
            float2 h6 = lstP[p6][128 + q];
            float2 h7 = lstP[p7][192 + q];
            float best = hm.x; int bj = __float_as_int(hm.y); int bs = 0;
            if (h4.x > best) { best = h4.x; bj = __float_as_int(h4.y); bs = 1; }
            if (h5.x > best) { best = h5.x; bj = __float_as_int(h5.y); bs = 2; }
            if (h6.x > best) { best = h6.x; bj = __float_as_int(h6.y); bs = 3; }
            if (h7.x > best) { best = h7.x; bj = __float_as_int(h7.y); bs = 4; }
            pm += (bs == 0); p4 += (bs == 1); p5 += (bs == 2); p6 += (bs == 3); p7 += (bs == 4);
            float4 nb = ctab[bj];
            coords[q][r] = nb;
            sx += nb.x; sy += nb.y; sz += nb.z;
        }
        const float mx = sx/16.f, my = sy/16.f, mz = sz/16.f;
        float sxx = 0, syy = 0, szz = 0, sd = 0;
        float dist[TOPK];
        #pragma unroll
        for (int r = 0; r < TOPK; ++r) {
            float4 nb = coords[q][r];
            float cx = nb.x - mx, cy = nb.y - my, cz = nb.z - mz;
            sxx += cx*cx; syy += cy*cy; szz += cz*cz;
            float dd = sqrtf(cx*cx + cy*cy + cz*cz);
            dist[r] = dd; sd += dd;
        }
        const float md = sd/16.f;
        float sdd = 0;
        #pragma unroll
        for (int r = 0; r < TOPK; ++r) { float t = dist[r] - md; sdd += t*t; }
        const float c00 = sxx/16.f, c11 = syy/16.f, c22 = szz/16.f;
        const float trace = c00 + c11 + c22;
        const float det = fmaxf(c00*c11*c22, 1e-8f);
        const float s0 = sqrtf(sxx/15.f), s1 = sqrtf(syy/15.f), s2 = sqrtf(szz/15.f);
        const float stdd = sqrtf(sdd/15.f);
        const float tt = trace + 1e-6f;
        float geo[10] = {trace, det, s0, s1, s2, md, stdd, s0/tt, s1/tt, s2/tt};

        float z1[32];
        #pragma unroll
        for (int jj = 0; jj < 32; ++jj) {
            float a = s_b1[jj];
            #pragma unroll
            for (int i = 0; i < 10; ++i) a = fmaf(geo[i], s_w1[i*32 + jj], a);
            z1[jj] = a;
        }
        float mzn = 0;
        #pragma unroll
        for (int jj = 0; jj < 32; ++jj) mzn += z1[jj];
        mzn /= 32.f;
        float vz = 0;
        #pragma unroll
        for (int jj = 0; jj < 32; ++jj) { float t = z1[jj] - mzn; vz += t*t; }
        vz /= 32.f;
        const float rs = 1.f/sqrtf(vz + 1e-5f);
        #pragma unroll
        for (int jj = 0; jj < 32; ++jj)
            z1[jj] = fmaxf((z1[jj]-mzn)*rs*s_lnw[jj] + s_lnb[jj], 0.f);
        float og[16];
        #pragma unroll
        for (int c = 0; c < 16; ++c) {
            float a = s_b2[c];
            #pragma unroll
            for (int i = 0; i < 32; ++i) a = fmaf(z1[i], s_w2[i*16 + c], a);
            og[c] = a;
        }
        float4* gout = (float4*)(geo_out + (size_t)qg*16);
        gout[0] = make_float4(og[0],  og[1],  og[2],  og[3]);
        gout[1] = make_float4(og[4],  og[5],  og[6],  og[7]);
        gout[2] = make_float4(og[8],  og[9],  og[10], og[11]);
        gout[3] = make_float4(og[12], og[13], og[14], og[15]);
    }
}

// ---------------------------------------------------------------------------
// kernel B: split-bf16 MFMA edge_pred + edge_refine (unchanged from R2).
// ---------------------------------------------------------------------------
__global__ __launch_bounds__(256, 1) void edge_k(
    const float* __restrict__ feat, const float* __restrict__ geo16,
    const unsigned short* __restrict__ rwh, const unsigned short* __restrict__ rwl,
    const unsigned short* __restrict__ ewh, const unsigned short* __restrict__ ewl,
    const float* __restrict__ e_b1, const float* __restrict__ e_lnw,
    const float* __restrict__ e_lnb, const float* __restrict__ e_w2,
    const float* __restrict__ e_b2,
    const float* __restrict__ r_b, const float* __restrict__ r_lnw,
    const float* __restrict__ r_lnb,
    float* __restrict__ out)
{
    __shared__ unsigned short sAh[64*296];
    __shared__ unsigned short sAl[64*296];
    __shared__ unsigned char  sB[65536];
    __shared__ float s_eb1[64], s_elnw[64], s_elnb[64], s_ew2[64];
    __shared__ float s_rb[256], s_rlnw[256], s_rlnb[256];
    __shared__ float s_ep[64], s_m[64], s_rs[64];
    __shared__ float sPx[256], sPq[256];

    const int tid  = threadIdx.x;
    const int lane = tid & 63;
    const int wv   = tid >> 6;
    const int lr   = lane & 15;
    const int lg   = lane >> 4;
    const int pbase = blockIdx.x * 64;

    if (tid < 64) { s_eb1[tid]=e_b1[tid]; s_elnw[tid]=e_lnw[tid]; s_elnb[tid]=e_lnb[tid]; s_ew2[tid]=e_w2[tid]; }
    s_rb[tid]=r_b[tid]; s_rlnw[tid]=r_lnw[tid]; s_rlnb[tid]=r_lnb[tid];

    const float4* f4 = (const float4*)(feat + (size_t)pbase*CF);
    #pragma unroll
    for (int it = 0; it < 16; ++it) {
        int v = tid + it*256;
        float4 x = f4[v];
        int row = v >> 6, c0 = (v & 63)*4;
        unsigned short h0=f2bf(x.x), h1=f2bf(x.y), h2=f2bf(x.z), h3=f2bf(x.w);
        unsigned short l0=f2bf(x.x-bf2f(h0)), l1=f2bf(x.y-bf2f(h1));
        unsigned short l2=f2bf(x.z-bf2f(h2)), l3=f2bf(x.w-bf2f(h3));
        *(ushort4*)&sAh[row*296 + c0] = make_ushort4(h0,h1,h2,h3);
        *(ushort4*)&sAl[row*296 + c0] = make_ushort4(l0,l1,l2,l3);
    }
    {
        const float4* g4 = (const float4*)(geo16 + (size_t)pbase*16);
        float4 x = g4[tid];
        int row = tid >> 2, c0 = 256 + (tid & 3)*4;
        unsigned short h0=f2bf(x.x), h1=f2bf(x.y), h2=f2bf(x.z), h3=f2bf(x.w);
        unsigned short l0=f2bf(x.x-bf2f(h0)), l1=f2bf(x.y-bf2f(h1));
        unsigned short l2=f2bf(x.z-bf2f(h2)), l3=f2bf(x.w-bf2f(h3));
        *(ushort4*)&sAh[row*296 + c0] = make_ushort4(h0,h1,h2,h3);
        *(ushort4*)&sAl[row*296 + c0] = make_ushort4(l0,l1,l2,l3);
        int zc = 272 + (tid & 3)*4;
        *(ushort4*)&sAh[row*296 + zc] = make_ushort4(0,0,0,0);
        *(ushort4*)&sAl[row*296 + zc] = make_ushort4(0,0,0,0);
    }

    auto stage3 = [&](int c, int buf) {
        const char* sh = (const char*)rwh + c*16384;
        const char* sl = (const char*)rwl + c*16384;
        char* dh = (char*)sB + buf*32768;
        char* dl = dh + 16384;
        #pragma unroll
        for (int i = 0; i < 4; ++i) {
            gl_lds16(sh + i*4096 + wv*1024 + lane*16, dh + i*4096 + wv*1024);
            gl_lds16(sl + i*4096 + wv*1024 + lane*16, dl + i*4096 + wv*1024);
        }
    };
    auto stage2 = [&](int c, int buf) {
        const char* sh = (const char*)ewh + c*4096;
        const char* sl = (const char*)ewl + c*4096;
        char* d = (char*)sB + 32768 + buf*8192;
        gl_lds16(sh + wv*1024 + lane*16, d + wv*1024);
        gl_lds16(sl + wv*1024 + lane*16, d + 4096 + wv*1024);
    };

    stage2(0, 0);
    stage3(0, 0);
    __syncthreads();

    f32x4 acc2[4];
    #pragma unroll
    for (int i = 0; i < 4; ++i) acc2[i] = (f32x4){0.f,0.f,0.f,0.f};
    const int arow2 = (wv*16 + lr)*296;
    for (int c = 0; c < 9; ++c) {
        if (c < 8) stage2(c+1, (c+1)&1);
        bf16x8 ah = *(const bf16x8*)&sAh[arow2 + c*32 + lg*8];
        bf16x8 al = *(const bf16x8*)&sAl[arow2 + c*32 + lg*8];
        const unsigned short* bb = (const unsigned short*)(sB + 32768 + (c&1)*8192);
        #pragma unroll
        for (int nt = 0; nt < 4; ++nt) {
            bf16x8 bh = *(const bf16x8*)&bb[nt*512 + lane*8];
            bf16x8 bl = *(const bf16x8*)&bb[2048 + nt*512 + lane*8];
            acc2[nt] = __builtin_amdgcn_mfma_f32_16x16x32_bf16(al, bh, acc2[nt], 0,0,0);
            acc2[nt] = __builtin_amdgcn_mfma_f32_16x16x32_bf16(ah, bl, acc2[nt], 0,0,0);
            acc2[nt] = __builtin_amdgcn_mfma_f32_16x16x32_bf16(ah, bh, acc2[nt], 0,0,0);
        }
        __syncthreads();
    }

    {
        float px[4] = {0,0,0,0}, pq[4] = {0,0,0,0};
        #pragma unroll
        for (int nt = 0; nt < 4; ++nt) {
            float bv = s_eb1[nt*16 + lr];
            #pragma unroll
            for (int j = 0; j < 4; ++j) {
                acc2[nt][j] += bv;
                px[j] += acc2[nt][j];
                pq[j] += acc2[nt][j]*acc2[nt][j];
            }
        }
        #pragma unroll
        for (int sw = 1; sw < 16; sw <<= 1) {
            #pragma unroll
            for (int j = 0; j < 4; ++j) { px[j] += __shfl_xor(px[j], sw); pq[j] += __shfl_xor(pq[j], sw); }
        }
        float mj[4], rj[4], dd[4] = {0,0,0,0};
        #pragma unroll
        for (int j = 0; j < 4; ++j) {
            mj[j] = px[j]*(1.f/64.f);
            float var = pq[j]*(1.f/64.f) - mj[j]*mj[j];
            rj[j] = rsqrtf(var + 1e-5f);
        }
        #pragma unroll
        for (int nt = 0; nt < 4; ++nt) {
            int col = nt*16 + lr;
            float lw = s_elnw[col], lb = s_elnb[col], w2 = s_ew2[col];
            #pragma unroll
            for (int j = 0; j < 4; ++j) {
                float h = fmaxf((acc2[nt][j]-mj[j])*rj[j]*lw + lb, 0.f);
                dd[j] = fmaf(h, w2, dd[j]);
            }
        }
        #pragma unroll
        for (int sw = 1; sw < 16; sw <<= 1) {
            #pragma unroll
            for (int j = 0; j < 4; ++j) dd[j] += __shfl_xor(dd[j], sw);
        }
        float eb2v = e_b2[0];
        #pragma unroll
        for (int j = 0; j < 4; ++j) {
            if (lr == j) {
                int row = wv*16 + lg*4 + j;
                float ep = 1.f/(1.f + expf(-(dd[j] + eb2v)));
                s_ep[row] = ep;
                out[EPOFF + pbase + row] = ep;
            }
        }
    }

    f32x4 acc3[4][4];
    #pragma unroll
    for (int mt = 0; mt < 4; ++mt)
        #pragma unroll
        for (int nt = 0; nt < 4; ++nt) acc3[mt][nt] = (f32x4){0.f,0.f,0.f,0.f};

    for (int c = 0; c < 8; ++c) {
        if (c < 7) stage3(c+1, (c+1)&1);
        bf16x8 ah[4], al[4];
        #pragma unroll
        for (int mt = 0; mt < 4; ++mt) {
            ah[mt] = *(const bf16x8*)&sAh[(mt*16+lr)*296 + c*32 + lg*8];
            al[mt] = *(const bf16x8*)&sAl[(mt*16+lr)*296 + c*32 + lg*8];
        }
        const unsigned short* bb = (const unsigned short*)(sB + (c&1)*32768);
        #pragma unroll
        for (int ntl = 0; ntl < 4; ++ntl) {
            int nt = wv*4 + ntl;
            bf16x8 bh = *(const bf16x8*)&bb[nt*512 + lane*8];
            bf16x8 bl = *(const bf16x8*)&bb[8192 + nt*512 + lane*8];
            #pragma unroll
            for (int mt = 0; mt < 4; ++mt) {
                acc3[mt][ntl] = __builtin_amdgcn_mfma_f32_16x16x32_bf16(al[mt], bh, acc3[mt][ntl], 0,0,0);
                acc3[mt][ntl] = __builtin_amdgcn_mfma_f32_16x16x32_bf16(ah[mt], bl, acc3[mt][ntl], 0,0,0);
                acc3[mt][ntl] = __builtin_amdgcn_mfma_f32_16x16x32_bf16(ah[mt], bh, acc3[mt][ntl], 0,0,0);
            }
        }
        __syncthreads();
    }

    float qx[4][4], qq[4][4];
    #pragma unroll
    for (int mt = 0; mt < 4; ++mt)
        #pragma unroll
        for (int j = 0; j < 4; ++j) { qx[mt][j] = 0.f; qq[mt][j] = 0.f; }
    #pragma unroll
    for (int ntl = 0; ntl < 4; ++ntl) {
        int col = (wv*4 + ntl)*16 + lr;
        float bv = s_rb[col];
        #pragma unroll
        for (int mt = 0; mt < 4; ++mt)
            #pragma unroll
            for (int j = 0; j < 4; ++j) {
                acc3[mt][ntl][j] += bv;
                float v = acc3[mt][ntl][j];
                qx[mt][j] += v; qq[mt][j] += v*v;
            }
    }
    #pragma unroll
    for (int sw = 1; sw < 16; sw <<= 1) {
        #pragma unroll
        for (int mt = 0; mt < 4; ++mt)
            #pragma unroll
            for (int j = 0; j < 4; ++j) { qx[mt][j] += __shfl_xor(qx[mt][j], sw); qq[mt][j] += __shfl_xor(qq[mt][j], sw); }
    }
    if (lr == 0) {
        #pragma unroll
        for (int mt = 0; mt < 4; ++mt)
            #pragma unroll
            for (int j = 0; j < 4; ++j) {
                int row = mt*16 + lg*4 + j;
                sPx[wv*64 + row] = qx[mt][j];
                sPq[wv*64 + row] = qq[mt][j];
            }
    }
    __syncthreads();
    if (tid < 64) {
        float Sx = sPx[tid] + sPx[64+tid] + sPx[128+tid] + sPx[192+tid];
        float Sq = sPq[tid] + sPq[64+tid] + sPq[128+tid] + sPq[192+tid];
        float m  = Sx*(1.f/256.f);
        float var = Sq*(1.f/256.f) - m*m;
        s_m[tid]  = m;
        s_rs[tid] = rsqrtf(var + 1e-5f);
    }
    __syncthreads();

    {
        float* sOut = (float*)sB;
        float lwv[4], lbv[4]; int colv[4];
        #pragma unroll
        for (int ntl = 0; ntl < 4; ++ntl) {
            colv[ntl] = (wv*4 + ntl)*16 + lr;
            lwv[ntl] = s_rlnw[colv[ntl]];
            lbv[ntl] = s_rlnb[colv[ntl]];
        }
        #pragma unroll
        for (int mt = 0; mt < 4; ++mt) {
            #pragma unroll
            for (int j = 0; j < 4; ++j) {
                int row = mt*16 + lg*4 + j;
                float m = s_m[row], rs = s_rs[row];
                #pragma unroll
                for (int ntl = 0; ntl < 4; ++ntl) {
                    float h = fmaxf((acc3[mt][ntl][j]-m)*rs*lwv[ntl] + lbv[ntl], 0.f);
                    sOut[row*256 + colv[ntl]] = h;
                }
            }
        }
    }
    __syncthreads();

    {
        const float* sOut = (const float*)sB;
        #pragma unroll
        for (int it = 0; it < 16; ++it) {
            int v = tid + it*256;
            int row = v >> 6, c0 = (v & 63)*4;
            float4 h4 = *(const float4*)&sOut[row*256 + c0];
            ushort4 hh = *(const ushort4*)&sAh[row*296 + c0];
            ushort4 ll = *(const ushort4*)&sAl[row*296 + c0];
            float ep = s_ep[row];
            float4 o;
            o.x = bf2f(hh.x) + bf2f(ll.x) + h4.x*ep;
            o.y = bf2f(hh.y) + bf2f(ll.y) + h4.y*ep;
            o.z = bf2f(hh.z) + bf2f(ll.z) + h4.z*ep;
            o.w = bf2f(hh.w) + bf2f(ll.w) + h4.w*ep;
            *(float4*)&out[(size_t)(pbase+row)*CF + c0] = o;
        }
    }
}

// ---------------------------------------------------------------------------
extern "C" void kernel_launch(void* const* d_in, const int* in_sizes, int n_in,
                              void* d_out, int out_size, void* d_ws, size_t ws_size,
                              hipStream_t stream) {
    (void)in_sizes; (void)n_in; (void)out_size; (void)ws_size;
    const float* xyz   = (const float*)d_in[0];
    const float* feat  = (const float*)d_in[1];
    const float* g_w1  = (const float*)d_in[2];
    const float* g_b1  = (const float*)d_in[3];
    const float* g_lnw = (const float*)d_in[4];
    const float* g_lnb = (const float*)d_in[5];
    const float* g_w2  = (const float*)d_in[6];
    const float* g_b2  = (const float*)d_in[7];
    const float* e_w1  = (const float*)d_in[8];
    const float* e_b1  = (const float*)d_in[9];
    const float* e_lnw = (const float*)d_in[10];
    const float* e_lnb = (const float*)d_in[11];
    const float* e_w2  = (const float*)d_in[12];
    const float* e_b2  = (const float*)d_in[13];
    const float* r_w   = (const float*)d_in[14];
    const float* r_b   = (const float*)d_in[15];
    const float* r_lnw = (const float*)d_in[16];
    const float* r_lnb = (const float*)d_in[17];
    float* out = (float*)d_out;

    char* ws = (char*)d_ws;
    float*          geo_ws = (float*)ws;                       // 2 MB
    float4*         tab    = (float4*)(ws + 0x200000);         // 512 KB
    unsigned short* rwh    = (unsigned short*)(ws + 0x280000); // 128 KB
    unsigned short* rwl    = (unsigned short*)(ws + 0x2A0000); // 128 KB
    unsigned short* ewh    = (unsigned short*)(ws + 0x2C0000); // 36 KB (64 KB slot)
    unsigned short* ewl    = (unsigned short*)(ws + 0x2D0000); // 36 KB

    hipLaunchKernelGGL(prep_k, dim3(256), dim3(256), 0, stream,
                       xyz, tab, r_w, e_w1, rwh, rwl, ewh, ewl);
    hipLaunchKernelGGL(knn_geo_k, dim3(TOTQ/64), dim3(512), 0, stream,
                       tab, g_w1, g_b1, g_lnw, g_lnb, g_w2, g_b2, geo_ws);
    hipLaunchKernelGGL(edge_k, dim3(TOTQ/64), dim3(256), 0, stream,
                       feat, geo_ws, rwh, rwl, ewh, ewl,
                       e_b1, e_lnw, e_lnb, e_w2, e_b2,
                       r_b, r_lnw, r_lnb, out);
}